// Round 10
// baseline (167.038 us; speedup 1.0000x reference)
//
#include <hip/hip_runtime.h>
#include <hip/hip_bf16.h>
#include <stdint.h>

#define TSEQ 4096
#define DM   1024
#define NH   16
#define HD   64
#define NQKV 3072

typedef unsigned short u16;
typedef unsigned int   u32;
typedef __attribute__((ext_vector_type(8)))  short bf16x8;
typedef __attribute__((ext_vector_type(4)))  float f32x4;
typedef __attribute__((ext_vector_type(4)))  int   i32x4;

static __device__ __forceinline__ u16 f2bf(float f) {
  u32 u = __float_as_uint(f);
  u32 r = (u + 0x7FFFu + ((u >> 16) & 1u)) >> 16;   // RNE
  return (u16)r;
}
static __device__ __forceinline__ float bf2f(u16 u) {
  return __uint_as_float(((u32)u) << 16);
}
static __device__ __forceinline__ u32 cvt_pk_bf16(float lo, float hi) {
  u32 r;
  asm("v_cvt_pk_bf16_f32 %0, %1, %2" : "=v"(r) : "v"(lo), "v"(hi));
  return r;
}
static __device__ __forceinline__ float fexp2(float x) {   // guaranteed v_exp_f32
  float r;
  asm("v_exp_f32 %0, %1" : "=v"(r) : "v"(x));
  return r;
}

#define GLL16(g, l) __builtin_amdgcn_global_load_lds( \
    (const __attribute__((address_space(1))) u32*)(g), \
    (__attribute__((address_space(3))) u32*)(l), 16, 0, 0)

// ---------------- fused cast fp32 -> bf16 for x, W_qkv, W_proj --------------
#define N4X  (TSEQ * DM / 4)
#define N4Q  (NQKV * DM / 4)
#define N4P  (DM * DM / 4)
__global__ void cast3_kernel(const float* __restrict__ x, u16* __restrict__ xo,
                             const float* __restrict__ wq, u16* __restrict__ wqo,
                             const float* __restrict__ wp, u16* __restrict__ wpo) {
  int i = blockIdx.x * 256 + threadIdx.x;
  const float* in; u16* out; int k;
  if (i < N4X)            { in = x;  out = xo;  k = i; }
  else if (i < N4X + N4Q) { in = wq; out = wqo; k = i - N4X; }
  else if (i < N4X + N4Q + N4P) { in = wp; out = wpo; k = i - N4X - N4Q; }
  else return;
  float4 v = ((const float4*)in)[k];
  ushort4 o;
  o.x = f2bf(v.x); o.y = f2bf(v.y); o.z = f2bf(v.z); o.w = f2bf(v.w);
  ((ushort4*)out)[k] = o;
}

// ---------------- RoPE sin/cos table [T][32] ----------------
__global__ void rope_table(float* __restrict__ sT, float* __restrict__ cT) {
  int i = blockIdx.x * 256 + threadIdx.x;   // t*32 + j
  int t = i >> 5, j = i & 31;
  float inv = exp2f((float)j * (-13.287712379549449f / 32.0f)); // 10000^(-j/32)
  float ang = (float)t * inv;
  sT[i] = sinf(ang);
  cT[i] = cosf(ang);
}

// ---------------- GEMM C[M,N] = A[M,K] * B[N,K]^T (bf16 in, fp32 acc) --------
template<int WRITE_BF16>
__global__ __launch_bounds__(256) void gemm_bt(const u16* __restrict__ A,
                                               const u16* __restrict__ B,
                                               void* __restrict__ Cout,
                                               int M, int N, int K)
{
  __shared__ __align__(16) u16 As[128 * 32];
  __shared__ __align__(16) u16 Bs[128 * 32];
  const int tid  = threadIdx.x;
  const int wave = tid >> 6, lane = tid & 63;
  const int l15  = lane & 15, lh = lane >> 4;
  const int wr   = wave >> 1, wc = wave & 1;

  const int nwg = gridDim.x * gridDim.y;
  int lin = blockIdx.y * gridDim.x + blockIdx.x;
  lin = (lin & 7) * (nwg >> 3) + (lin >> 3);          // nwg % 8 == 0
  const size_t bm = (size_t)(lin / gridDim.x);
  const size_t bn = (size_t)(lin % gridDim.x);

  f32x4 acc[4][4] = {};

  const u16* Ab = A + bm * 128 * (size_t)K;
  const u16* Bb = B + bn * 128 * (size_t)K;

  for (int k0 = 0; k0 < K; k0 += 32) {
    __syncthreads();
#pragma unroll
    for (int j = 0; j < 2; ++j) {
      const int ch = j * 4 + wave;            // 8 chunks of 1024B per tile
      const int e  = ch * 512 + lane * 8;     // element within tile (row-major [128][32])
      const int r  = e >> 5, c = e & 31;
      GLL16(Ab + (size_t)r * K + k0 + c, As + ch * 512);
      GLL16(Bb + (size_t)r * K + k0 + c, Bs + ch * 512);
    }
    asm volatile("s_waitcnt vmcnt(0)" ::: "memory");
    __syncthreads();

    bf16x8 af[4], bfr[4];
#pragma unroll
    for (int m = 0; m < 4; ++m)
      af[m] = *(const bf16x8*)(As + (wr * 64 + m * 16 + l15) * 32 + lh * 8);
#pragma unroll
    for (int n = 0; n < 4; ++n)
      bfr[n] = *(const bf16x8*)(Bs + (wc * 64 + n * 16 + l15) * 32 + lh * 8);
#pragma unroll
    for (int m = 0; m < 4; ++m)
#pragma unroll
      for (int n = 0; n < 4; ++n)
        acc[m][n] = __builtin_amdgcn_mfma_f32_16x16x32_bf16(af[m], bfr[n], acc[m][n], 0, 0, 0);
  }

#pragma unroll
  for (int m = 0; m < 4; ++m)
#pragma unroll
    for (int n = 0; n < 4; ++n)
#pragma unroll
      for (int r = 0; r < 4; ++r) {
        size_t row = bm * 128 + wr * 64 + m * 16 + lh * 4 + r;
        size_t col = bn * 128 + wc * 64 + n * 16 + l15;
        float v = acc[m][n][r];
        if (WRITE_BF16) ((u16*)Cout)[row * N + col] = f2bf(v);
        else            ((float*)Cout)[row * N + col] = v;
      }
}

// ---------------- RoPE + head-split into 16x16-MFMA-fragment layouts --------
// Q,K (B/A-frag, 16 t-rows x 32 d): idx = (((h*256+(t>>4))*2+(d>>5))*64 + (t&15)+((d>>3)&3)*16)*8 + (d&7)
// V^T (A-frag, 16 d-rows x 32 kv):  idx = ((((h*64+(t>>6))*4+(d>>4))*2+((t>>5)&1))*64 + (d&15)+((t>>3)&3)*16)*8 + (t&7)
__global__ void rope_reorg(const u16* __restrict__ qkv,
                           const float* __restrict__ sT, const float* __restrict__ cT,
                           u16* __restrict__ Qo, u16* __restrict__ Ko, u16* __restrict__ Vo)
{
  int idx = blockIdx.x * 256 + threadIdx.x;   // (t*16 + h)*32 + j
  int j = idx & 31;
  int h = (idx >> 5) & 15;
  int t = idx >> 9;
  const float QSC = 0.125f * 1.4426950408889634f;  // 1/sqrt(64) * log2(e)
  float s = sT[t * 32 + j], c = cT[t * 32 + j];
  const u16* row = qkv + (size_t)t * NQKV + h * HD;
  float q1 = bf2f(row[j]),        q2 = bf2f(row[j + 32]);
  float k1 = bf2f(row[DM + j]),   k2 = bf2f(row[DM + j + 32]);
  float qa = (q1 * c - q2 * s) * QSC, qb2 = (q2 * c + q1 * s) * QSC;
  float ka = k1 * c - k2 * s,         kb2 = k2 * c + k1 * s;

  int d0 = j, d1 = j + 32;
  size_t qk0 = ((((size_t)h * 256 + (t >> 4)) * 2 + (d0 >> 5)) * 64 +
                (t & 15) + ((d0 >> 3) & 3) * 16) * 8 + (d0 & 7);
  size_t qk1 = ((((size_t)h * 256 + (t >> 4)) * 2 + (d1 >> 5)) * 64 +
                (t & 15) + ((d1 >> 3) & 3) * 16) * 8 + (d1 & 7);
  Qo[qk0] = f2bf(qa);  Qo[qk1] = f2bf(qb2);
  Ko[qk0] = f2bf(ka);  Ko[qk1] = f2bf(kb2);

  size_t vt = (size_t)((t >> 5) & 1) * 64 + ((t >> 3) & 3) * 16;  // kv-chunk+colgrp part
  size_t vbase = (((size_t)h * 64 + (t >> 6)) * 8) * 64;          // 8 blocks per kv-tile
  size_t v0 = (vbase + (size_t)(d0 >> 4) * 128 + vt + (d0 & 15)) * 8 + (t & 7);
  size_t v1 = (vbase + (size_t)(d1 >> 4) * 128 + vt + (d1 & 15)) * 8 + (t & 7);
  Vo[v0] = row[2 * DM + j];
  Vo[v1] = row[2 * DM + j + 32];
}

// ---------------- causal flash attention, 8 waves, kv-split G=3 -------------
// grid 768 blocks (= exactly 3/CU, 24 waves/CU = 75% cap) x 512 thr.
// Block: q-tile of 128 rows (8 waves x 16), phases {qt=pr, 31-pr}, kv tiles
// [kt0,kt1) of group g (~23 steps total). Frag-linear gload_lds staging
// (1 GLL/thread/array), dbuf, 1 barrier/step, ZERO cross-lane steady state,
// NO max tracking (group-first-tile bias only; merge weights kill masked rows).
// Epilogue: normalized partial O (bf16 row-major) + per-q (m,l); merge_o sums.
__global__ __launch_bounds__(512) void fattn(const u16* __restrict__ Qf,
                                             const u16* __restrict__ Kf,
                                             const u16* __restrict__ Vf,
                                             u16* __restrict__ Opart,
                                             float2* __restrict__ lmb)
{
  __shared__ __align__(16) u16 Ks[2][4096];
  __shared__ __align__(16) u16 Vs[2][4096];
  __shared__ __align__(16) u16 Ps[8][1024];

  const int bid = blockIdx.x;
  const int h   = bid & (NH - 1);            // heads spread over XCDs
  const int t16 = bid >> 4;                  // 0..47
  const int g   = t16 % 3;                   // kv group
  const int pr  = t16 / 3;                   // 0..15
  const int tid = threadIdx.x;
  const int wave = tid >> 6, lane = tid & 63;
  const int l15 = lane & 15, lh = lane >> 4;
  const int lb  = lane * 8;                  // linear fragment offset (elems)

  const size_t hbase = (size_t)h * (TSEQ * HD);
  const u16* kg = Kf + hbase;
  const u16* vg = Vf + hbase;
  u16* const Og = Opart + (size_t)g * (TSEQ * DM);

  // P store offsets (elems), per n-tile: frag-linear B layout
  u16* const pw = &Ps[wave][0];
  int pso[4];
#pragma unroll
  for (int n = 0; n < 4; ++n)
    pso[n] = (n >> 1) * 512 + (((2 * n + (lh >> 1)) & 3) * 16 + l15) * 8 + (lh & 1) * 4;

  for (int ph = 0; ph < 2; ++ph) {
    const int qt  = ph ? (31 - pr) : pr;     // 128-row tile index
    const int q0  = qt * 128;
    const int ntiles = 2 * qt + 2;           // 64-kv tiles covering [0, q0+128)
    const int kt0 = (g * ntiles) / 3;
    const int kt1 = ((g + 1) * ntiles) / 3;
    const int qw0 = q0 + wave * 16;          // this wave's first q row
    const int qgl = qw0 + l15;               // this lane's q row (global)

    f32x4 oacc[4] = {};
    float mrun = -3.0e38f, lrunp = 0.f;      // lrunp is LANE-PARTIAL

    if (kt0 < kt1) {
      // Q fragments (B-operand)
      bf16x8 qf0, qf1;
      {
        const u16* qp = Qf + hbase + (size_t)(qt * 8 + wave) * 1024;
        qf0 = *(const bf16x8*)(qp + lb);
        qf1 = *(const bf16x8*)(qp + 512 + lb);
      }

      // prologue: stage tile kt0 -> buf 0 (512 thr: 1 GLL each per array)
      GLL16(kg + (size_t)kt0 * 4096 + tid * 8, &Ks[0][tid * 8]);
      GLL16(vg + (size_t)kt0 * 4096 + tid * 8, &Vs[0][tid * 8]);
      asm volatile("s_waitcnt vmcnt(0)" ::: "memory");
      __syncthreads();

      for (int kt = kt0; kt < kt1; ++kt) {
        const int cur = (kt - kt0) & 1;
        if (kt + 1 < kt1) {                  // stage next tile during compute
          GLL16(kg + (size_t)(kt + 1) * 4096 + tid * 8, &Ks[cur ^ 1][tid * 8]);
          GLL16(vg + (size_t)(kt + 1) * 4096 + tid * 8, &Vs[cur ^ 1][tid * 8]);
        }
        const u16* kb = Ks[cur];
        const u16* vb = Vs[cur];
        const int kv0 = kt * 64;

        // ---- S^T = mfma(K,Q), C-init = -mrun (kt>kt0)
        const float mz = (kt == kt0) ? 0.f : -mrun;
        f32x4 sacc[4];
        __builtin_amdgcn_s_setprio(1);
#pragma unroll
        for (int n = 0; n < 4; ++n) {
          bf16x8 kf0 = *(const bf16x8*)(kb + (n * 2 + 0) * 512 + lb);
          bf16x8 kf1 = *(const bf16x8*)(kb + (n * 2 + 1) * 512 + lb);
          f32x4 z = {mz, mz, mz, mz};
          sacc[n] = __builtin_amdgcn_mfma_f32_16x16x32_bf16(kf0, qf0, z, 0, 0, 0);
          sacc[n] = __builtin_amdgcn_mfma_f32_16x16x32_bf16(kf1, qf1, sacc[n], 0, 0, 0);
        }
        __builtin_amdgcn_s_setprio(0);

        if (kv0 + 63 > qw0) {                // wave-uniform: diagonal-ish tile
#pragma unroll
          for (int n = 0; n < 4; ++n)
#pragma unroll
            for (int r = 0; r < 4; ++r)
              if (kv0 + n * 16 + lh * 4 + r > qgl) sacc[n][r] = -3.0e38f;
        }

        if (kt == kt0) {                     // group-first tile: row max bias
          float tm = fmaxf(fmaxf(sacc[0][0], sacc[0][1]), fmaxf(sacc[0][2], sacc[0][3]));
#pragma unroll
          for (int n = 1; n < 4; ++n)
            tm = fmaxf(tm, fmaxf(fmaxf(sacc[n][0], sacc[n][1]), fmaxf(sacc[n][2], sacc[n][3])));
          tm = fmaxf(tm, __shfl_xor(tm, 16));
          tm = fmaxf(tm, __shfl_xor(tm, 32));
          mrun = tm;
#pragma unroll
          for (int n = 0; n < 4; ++n)
#pragma unroll
            for (int r = 0; r < 4; ++r) sacc[n][r] -= mrun;   // -3e38-(-3e38)=0 ok
        }

        // ---- exp + lane-partial sum (no max tracking, no cross-lane ops)
        float rs = 0.f;
#pragma unroll
        for (int n = 0; n < 4; ++n) {
          float p0 = fexp2(sacc[n][0]);
          float p1 = fexp2(sacc[n][1]);
          float p2 = fexp2(sacc[n][2]);
          float p3 = fexp2(sacc[n][3]);
          rs += (p0 + p1) + (p2 + p3);
          uint2 wv;
          wv.x = cvt_pk_bf16(p0, p1);
          wv.y = cvt_pk_bf16(p2, p3);
          *(uint2*)(pw + pso[n]) = wv;
        }
        lrunp += rs;

        // ---- PV: O^T += V * P   (oacc[dn]: d = dn*16+lh*4+r, q = l15)
        __builtin_amdgcn_s_setprio(1);
#pragma unroll
        for (int kk = 0; kk < 2; ++kk) {
          bf16x8 pf = *(const bf16x8*)(pw + kk * 512 + lb);
#pragma unroll
          for (int dn = 0; dn < 4; ++dn) {
            bf16x8 vf = *(const bf16x8*)(vb + (dn * 2 + kk) * 512 + lb);
            oacc[dn] = __builtin_amdgcn_mfma_f32_16x16x32_bf16(vf, pf, oacc[dn], 0, 0, 0);
          }
        }
        __builtin_amdgcn_s_setprio(0);

        asm volatile("s_waitcnt vmcnt(0)" ::: "memory");
        __syncthreads();
      }
    }

    // ---- epilogue: reduce lane-partial l, store partial O + (m,l) ----
    {
      float lr = lrunp;
      lr += __shfl_xor(lr, 16);
      lr += __shfl_xor(lr, 32);

      if (kt0 < kt1) {
        float inv = 1.f / lr;
#pragma unroll
        for (int dn = 0; dn < 4; ++dn) {
          int d0 = dn * 16 + lh * 4;
          uint2 wv;
          wv.x = cvt_pk_bf16(oacc[dn][0] * inv, oacc[dn][1] * inv);
          wv.y = cvt_pk_bf16(oacc[dn][2] * inv, oacc[dn][3] * inv);
          *(uint2*)(pw + l15 * 64 + ((d0 + l15 * 8) & 63)) = wv;
        }
        asm volatile("s_waitcnt lgkmcnt(0)" ::: "memory");
        __builtin_amdgcn_sched_barrier(0);
        const int q  = lane >> 2;            // 16 rows x 4 d-chunks of 16
        const int dc = (lane & 3) * 16;
#pragma unroll
        for (int half = 0; half < 2; ++half) {
          int ds = dc + half * 8;
          i32x4 v = *(const i32x4*)(pw + q * 64 + ((ds + q * 8) & 63));
          *(i32x4*)(Og + (size_t)(qw0 + q) * DM + h * HD + ds) = v;
        }
      }
      if (lh == 0) {                         // per-q stats (m log2-domain, l)
        float2 s; s.x = mrun; s.y = lr;
        lmb[((size_t)g * NH + h) * TSEQ + qgl] = s;
      }
    }
  }
}

// ---------------- merge the three kv-group partials ----------------
// O[q][h*64+d] = sum_g a_g * O_g,  a_g = 2^(m_g - m) * l_g / sum
__global__ void merge_o(const u16* __restrict__ Opart, const float2* __restrict__ lmb,
                        u16* __restrict__ Ob) {
  int i = blockIdx.x * 256 + threadIdx.x;    // [0, TSEQ*DM/8)
  int q  = i >> 7;
  int c8 = (i & 127) * 8;
  int h  = c8 >> 6;
  float2 s0 = lmb[(size_t)h * TSEQ + q];
  float2 s1 = lmb[((size_t)NH + h) * TSEQ + q];
  float2 s2 = lmb[((size_t)2 * NH + h) * TSEQ + q];
  float m  = fmaxf(s0.x, fmaxf(s1.x, s2.x));
  float w0 = fexp2(s0.x - m) * s0.y;
  float w1 = fexp2(s1.x - m) * s1.y;
  float w2 = fexp2(s2.x - m) * s2.y;
  float inv = 1.f / (w0 + w1 + w2);
  float a0 = w0 * inv, a1 = w1 * inv, a2 = w2 * inv;
  size_t off = (size_t)q * DM + c8;
  i32x4 u0 = *(const i32x4*)(Opart + off);
  i32x4 u1 = *(const i32x4*)(Opart + (size_t)(TSEQ * DM) + off);
  i32x4 u2 = *(const i32x4*)(Opart + 2 * (size_t)(TSEQ * DM) + off);
  const u16* p0 = (const u16*)&u0;
  const u16* p1 = (const u16*)&u1;
  const u16* p2 = (const u16*)&u2;
  union { u16 o[8]; i32x4 v; } r;
#pragma unroll
  for (int e = 0; e < 8; ++e)
    r.o[e] = f2bf(a0 * bf2f(p0[e]) + a1 * bf2f(p1[e]) + a2 * bf2f(p2[e]));
  *(i32x4*)(Ob + off) = r.v;
}

extern "C" void kernel_launch(void* const* d_in, const int* in_sizes, int n_in,
                              void* d_out, int out_size, void* d_ws, size_t ws_size,
                              hipStream_t stream)
{
  const float* x     = (const float*)d_in[0];
  const float* wqkv  = (const float*)d_in[1];
  const float* wproj = (const float*)d_in[2];
  float* out = (float*)d_out;

  char* ws = (char*)d_ws;
  size_t off = 0;
  u16* xb   = (u16*)(ws + off); off += (size_t)TSEQ * DM * 2;
  u16* wqb  = (u16*)(ws + off); off += (size_t)NQKV * DM * 2;
  u16* wpb  = (u16*)(ws + off); off += (size_t)DM * DM * 2;
  u16* qkvb = (u16*)(ws + off); off += (size_t)TSEQ * NQKV * 2;
  u16* Qb   = (u16*)(ws + off); off += (size_t)NH * TSEQ * HD * 2;
  u16* Kb   = (u16*)(ws + off); off += (size_t)NH * TSEQ * HD * 2;
  u16* Vb   = (u16*)(ws + off); off += (size_t)NH * TSEQ * HD * 2;
  u16* Ob   = (u16*)(ws + off); off += (size_t)TSEQ * DM * 2;
  float* sT = (float*)(ws + off); off += (size_t)TSEQ * 32 * 4;
  float* cT = (float*)(ws + off); off += (size_t)TSEQ * 32 * 4;

  // kv-split partials alias DEAD buffers: 3 x 8MB = 24MB fits qkvb exactly
  // (dead after rope_reorg); stats 1.5MB alias wqb (dead after gemm1).
  u16*    Opart = qkvb;
  float2* lmb   = (float2*)wqb;

  const int ncast = N4X + N4Q + N4P;
  cast3_kernel<<<(ncast + 255) / 256, 256, 0, stream>>>(x, xb, wqkv, wqb, wproj, wpb);
  rope_table<<<(TSEQ * 32) / 256, 256, 0, stream>>>(sT, cT);

  gemm_bt<1><<<dim3(NQKV / 128, TSEQ / 128), 256, 0, stream>>>(xb, wqb, qkvb, TSEQ, NQKV, DM);

  rope_reorg<<<(TSEQ * NH * 32) / 256, 256, 0, stream>>>(qkvb, sT, cT, Qb, Kb, Vb);

  fattn<<<NH * 48, 512, 0, stream>>>(Qb, Kb, Vb, Opart, lmb);

  merge_o<<<(TSEQ * DM / 8) / 256, 256, 0, stream>>>(Opart, lmb, Ob);

  gemm_bt<0><<<dim3(DM / 128, TSEQ / 128), 256, 0, stream>>>(Ob, wpb, out, TSEQ, DM, DM);
}

// Round 11
// 167.015 us; speedup vs baseline: 1.0001x; 1.0001x over previous
//
#include <hip/hip_runtime.h>
#include <hip/hip_bf16.h>
#include <stdint.h>

#define TSEQ 4096
#define DM   1024
#define NH   16
#define HD   64
#define NQKV 3072

typedef unsigned short u16;
typedef unsigned int   u32;
typedef __attribute__((ext_vector_type(8)))  short bf16x8;
typedef __attribute__((ext_vector_type(4)))  float f32x4;
typedef __attribute__((ext_vector_type(4)))  int   i32x4;

static __device__ __forceinline__ u16 f2bf(float f) {
  u32 u = __float_as_uint(f);
  u32 r = (u + 0x7FFFu + ((u >> 16) & 1u)) >> 16;   // RNE
  return (u16)r;
}
static __device__ __forceinline__ float bf2f(u16 u) {
  return __uint_as_float(((u32)u) << 16);
}
static __device__ __forceinline__ u32 cvt_pk_bf16(float lo, float hi) {
  u32 r;
  asm("v_cvt_pk_bf16_f32 %0, %1, %2" : "=v"(r) : "v"(lo), "v"(hi));
  return r;
}
static __device__ __forceinline__ float fexp2(float x) {   // guaranteed v_exp_f32
  float r;
  asm("v_exp_f32 %0, %1" : "=v"(r) : "v"(x));
  return r;
}

#define GLL16(g, l) __builtin_amdgcn_global_load_lds( \
    (const __attribute__((address_space(1))) u32*)(g), \
    (__attribute__((address_space(3))) u32*)(l), 16, 0, 0)

// ---------------- fused cast fp32 -> bf16 for x, W_qkv, W_proj --------------
#define N4X  (TSEQ * DM / 4)
#define N4Q  (NQKV * DM / 4)
#define N4P  (DM * DM / 4)
__global__ void cast3_kernel(const float* __restrict__ x, u16* __restrict__ xo,
                             const float* __restrict__ wq, u16* __restrict__ wqo,
                             const float* __restrict__ wp, u16* __restrict__ wpo) {
  int i = blockIdx.x * 256 + threadIdx.x;
  const float* in; u16* out; int k;
  if (i < N4X)            { in = x;  out = xo;  k = i; }
  else if (i < N4X + N4Q) { in = wq; out = wqo; k = i - N4X; }
  else if (i < N4X + N4Q + N4P) { in = wp; out = wpo; k = i - N4X - N4Q; }
  else return;
  float4 v = ((const float4*)in)[k];
  ushort4 o;
  o.x = f2bf(v.x); o.y = f2bf(v.y); o.z = f2bf(v.z); o.w = f2bf(v.w);
  ((ushort4*)out)[k] = o;
}

// ---------------- RoPE sin/cos table [T][32] ----------------
__global__ void rope_table(float* __restrict__ sT, float* __restrict__ cT) {
  int i = blockIdx.x * 256 + threadIdx.x;   // t*32 + j
  int t = i >> 5, j = i & 31;
  float inv = exp2f((float)j * (-13.287712379549449f / 32.0f)); // 10000^(-j/32)
  float ang = (float)t * inv;
  sT[i] = sinf(ang);
  cT[i] = cosf(ang);
}

// ---------------- GEMM C[M,N] = A[M,K] * B[N,K]^T (bf16 in, fp32 acc) --------
template<int WRITE_BF16>
__global__ __launch_bounds__(256) void gemm_bt(const u16* __restrict__ A,
                                               const u16* __restrict__ B,
                                               void* __restrict__ Cout,
                                               int M, int N, int K)
{
  __shared__ __align__(16) u16 As[128 * 32];
  __shared__ __align__(16) u16 Bs[128 * 32];
  const int tid  = threadIdx.x;
  const int wave = tid >> 6, lane = tid & 63;
  const int l15  = lane & 15, lh = lane >> 4;
  const int wr   = wave >> 1, wc = wave & 1;

  const int nwg = gridDim.x * gridDim.y;
  int lin = blockIdx.y * gridDim.x + blockIdx.x;
  lin = (lin & 7) * (nwg >> 3) + (lin >> 3);          // nwg % 8 == 0
  const size_t bm = (size_t)(lin / gridDim.x);
  const size_t bn = (size_t)(lin % gridDim.x);

  f32x4 acc[4][4] = {};

  const u16* Ab = A + bm * 128 * (size_t)K;
  const u16* Bb = B + bn * 128 * (size_t)K;

  for (int k0 = 0; k0 < K; k0 += 32) {
    __syncthreads();
#pragma unroll
    for (int j = 0; j < 2; ++j) {
      const int ch = j * 4 + wave;            // 8 chunks of 1024B per tile
      const int e  = ch * 512 + lane * 8;     // element within tile (row-major [128][32])
      const int r  = e >> 5, c = e & 31;
      GLL16(Ab + (size_t)r * K + k0 + c, As + ch * 512);
      GLL16(Bb + (size_t)r * K + k0 + c, Bs + ch * 512);
    }
    asm volatile("s_waitcnt vmcnt(0)" ::: "memory");
    __syncthreads();

    bf16x8 af[4], bfr[4];
#pragma unroll
    for (int m = 0; m < 4; ++m)
      af[m] = *(const bf16x8*)(As + (wr * 64 + m * 16 + l15) * 32 + lh * 8);
#pragma unroll
    for (int n = 0; n < 4; ++n)
      bfr[n] = *(const bf16x8*)(Bs + (wc * 64 + n * 16 + l15) * 32 + lh * 8);
#pragma unroll
    for (int m = 0; m < 4; ++m)
#pragma unroll
      for (int n = 0; n < 4; ++n)
        acc[m][n] = __builtin_amdgcn_mfma_f32_16x16x32_bf16(af[m], bfr[n], acc[m][n], 0, 0, 0);
  }

#pragma unroll
  for (int m = 0; m < 4; ++m)
#pragma unroll
    for (int n = 0; n < 4; ++n)
#pragma unroll
      for (int r = 0; r < 4; ++r) {
        size_t row = bm * 128 + wr * 64 + m * 16 + lh * 4 + r;
        size_t col = bn * 128 + wc * 64 + n * 16 + l15;
        float v = acc[m][n][r];
        if (WRITE_BF16) ((u16*)Cout)[row * N + col] = f2bf(v);
        else            ((float*)Cout)[row * N + col] = v;
      }
}

// ---------------- RoPE + head-split into 16x16-MFMA-fragment layouts --------
// Q,K (B/A-frag, 16 t-rows x 32 d): idx = (((h*256+(t>>4))*2+(d>>5))*64 + (t&15)+((d>>3)&3)*16)*8 + (d&7)
// V^T (A-frag, 16 d-rows x 32 kv):  idx = ((((h*64+(t>>6))*4+(d>>4))*2+((t>>5)&1))*64 + (d&15)+((t>>3)&3)*16)*8 + (t&7)
__global__ void rope_reorg(const u16* __restrict__ qkv,
                           const float* __restrict__ sT, const float* __restrict__ cT,
                           u16* __restrict__ Qo, u16* __restrict__ Ko, u16* __restrict__ Vo)
{
  int idx = blockIdx.x * 256 + threadIdx.x;   // (t*16 + h)*32 + j
  int j = idx & 31;
  int h = (idx >> 5) & 15;
  int t = idx >> 9;
  const float QSC = 0.125f * 1.4426950408889634f;  // 1/sqrt(64) * log2(e)
  float s = sT[t * 32 + j], c = cT[t * 32 + j];
  const u16* row = qkv + (size_t)t * NQKV + h * HD;
  float q1 = bf2f(row[j]),        q2 = bf2f(row[j + 32]);
  float k1 = bf2f(row[DM + j]),   k2 = bf2f(row[DM + j + 32]);
  float qa = (q1 * c - q2 * s) * QSC, qb2 = (q2 * c + q1 * s) * QSC;
  float ka = k1 * c - k2 * s,         kb2 = k2 * c + k1 * s;

  int d0 = j, d1 = j + 32;
  size_t qk0 = ((((size_t)h * 256 + (t >> 4)) * 2 + (d0 >> 5)) * 64 +
                (t & 15) + ((d0 >> 3) & 3) * 16) * 8 + (d0 & 7);
  size_t qk1 = ((((size_t)h * 256 + (t >> 4)) * 2 + (d1 >> 5)) * 64 +
                (t & 15) + ((d1 >> 3) & 3) * 16) * 8 + (d1 & 7);
  Qo[qk0] = f2bf(qa);  Qo[qk1] = f2bf(qb2);
  Ko[qk0] = f2bf(ka);  Ko[qk1] = f2bf(kb2);

  size_t vt = (size_t)((t >> 5) & 1) * 64 + ((t >> 3) & 3) * 16;  // kv-half + colgrp
  size_t vbase = (((size_t)h * 64 + (t >> 6)) * 8) * 64;          // 8 blocks per 64-kv tile
  size_t v0 = (vbase + (size_t)(d0 >> 4) * 128 + vt + (d0 & 15)) * 8 + (t & 7);
  size_t v1 = (vbase + (size_t)(d1 >> 4) * 128 + vt + (d1 & 15)) * 8 + (t & 7);
  Vo[v0] = row[2 * DM + j];
  Vo[v1] = row[2 * DM + j + 32];
}

// ---------------- causal flash attention, KVBLK=32, 4 waves, G=4 ------------
// grid 2048 blocks (= 8/CU via 20KB LDS, 32 waves/CU = 100% cap) x 256 thr.
// Block: q-tile 64 rows (4 waves x 16), phases {qt=pr, 63-pr}, 32-row kv tiles
// [kt0,kt1) of group g (~33 steps). Frag-linear gload_lds staging, dbuf,
// 1 barrier/step, zero cross-lane steady state, no max tracking (group-first
// bias; merge weights kill fully-masked rows exactly: 2^(-3e38-m)*l = 0).
__global__ __launch_bounds__(256, 8) void fattn(const u16* __restrict__ Qf,
                                                const u16* __restrict__ Kf,
                                                const u16* __restrict__ Vf,
                                                u16* __restrict__ Opart012,
                                                u16* __restrict__ Opart3,
                                                float2* __restrict__ lmb)
{
  __shared__ __align__(16) u16 Ks[2][2048];
  __shared__ __align__(16) u16 Vs[2][2048];
  __shared__ __align__(16) u16 Ps[4][512];

  const int bid = blockIdx.x;
  const int h   = bid & (NH - 1);            // h, h+8 share XCD (bid&7)
  const int g   = (bid >> 4) & 3;            // kv group
  const int pr  = bid >> 6;                  // 0..31
  const int tid = threadIdx.x;
  const int wave = tid >> 6, lane = tid & 63;
  const int l15 = lane & 15, lh = lane >> 4;
  const int lb  = lane * 8;                  // linear fragment offset (elems)

  const size_t hbase = (size_t)h * (TSEQ * HD);
  const u16* kg = Kf + hbase;
  const u16* vg = Vf + hbase;
  u16* const Og = (g < 3) ? (Opart012 + (size_t)g * (TSEQ * DM))
                          : Opart3;

  // P store offsets (elems): B-frag linear layout [32 kv][16 q] per wave
  u16* const pw = &Ps[wave][0];
  int pso[2];
#pragma unroll
  for (int n = 0; n < 2; ++n)
    pso[n] = n * 256 + ((lh >> 1) * 16 + l15) * 8 + (lh & 1) * 4;

  for (int ph = 0; ph < 2; ++ph) {
    const int qt  = ph ? (63 - pr) : pr;     // 64-row q-tile index
    const int q0  = qt * 64;
    const int ntiles = 2 * qt + 2;           // 32-kv tiles covering [0, q0+64)
    const int kt0 = (g * ntiles) >> 2;
    const int kt1 = ((g + 1) * ntiles) >> 2;
    const int qw0 = q0 + wave * 16;          // this wave's first q row
    const int qgl = qw0 + l15;               // this lane's q row (global)

    f32x4 oacc[4] = {};
    float mrun = -3.0e38f, lrunp = 0.f;      // LANE-PARTIAL l

    if (kt0 < kt1) {
      // Q fragments (B-operand)
      bf16x8 qf0, qf1;
      {
        const u16* qp = Qf + hbase + (size_t)(qt * 4 + wave) * 1024;
        qf0 = *(const bf16x8*)(qp + lb);
        qf1 = *(const bf16x8*)(qp + 512 + lb);
      }

      // prologue: stage tile kt0 -> buf 0
      GLL16(kg + (size_t)kt0 * 2048 + tid * 8, &Ks[0][tid * 8]);
      GLL16(vg + (size_t)(kt0 >> 1) * 4096 + (wave * 2 + (kt0 & 1)) * 512 + lane * 8,
            &Vs[0][tid * 8]);
      asm volatile("s_waitcnt vmcnt(0)" ::: "memory");
      __syncthreads();

      for (int kt = kt0; kt < kt1; ++kt) {
        const int cur = (kt - kt0) & 1;
        if (kt + 1 < kt1) {                  // stage next tile during compute
          const int kn = kt + 1;
          GLL16(kg + (size_t)kn * 2048 + tid * 8, &Ks[cur ^ 1][tid * 8]);
          GLL16(vg + (size_t)(kn >> 1) * 4096 + (wave * 2 + (kn & 1)) * 512 + lane * 8,
                &Vs[cur ^ 1][tid * 8]);
        }
        const u16* kb = Ks[cur];
        const u16* vb = Vs[cur];
        const int kv0 = kt * 32;

        // ---- S^T = mfma(K,Q), C-init = -mrun (kt>kt0)
        const float mz = (kt == kt0) ? 0.f : -mrun;
        f32x4 sacc[2];
        __builtin_amdgcn_s_setprio(1);
#pragma unroll
        for (int n = 0; n < 2; ++n) {
          bf16x8 kf0 = *(const bf16x8*)(kb + (n * 2 + 0) * 512 + lb);
          bf16x8 kf1 = *(const bf16x8*)(kb + (n * 2 + 1) * 512 + lb);
          f32x4 z = {mz, mz, mz, mz};
          sacc[n] = __builtin_amdgcn_mfma_f32_16x16x32_bf16(kf0, qf0, z, 0, 0, 0);
          sacc[n] = __builtin_amdgcn_mfma_f32_16x16x32_bf16(kf1, qf1, sacc[n], 0, 0, 0);
        }
        __builtin_amdgcn_s_setprio(0);

        if (kv0 + 31 > qw0) {                // wave-uniform: diagonal-ish tile
#pragma unroll
          for (int n = 0; n < 2; ++n)
#pragma unroll
            for (int r = 0; r < 4; ++r)
              if (kv0 + n * 16 + lh * 4 + r > qgl) sacc[n][r] = -3.0e38f;
        }

        if (kt == kt0) {                     // group-first tile: row max bias
          float tm = fmaxf(fmaxf(sacc[0][0], sacc[0][1]), fmaxf(sacc[0][2], sacc[0][3]));
          tm = fmaxf(tm, fmaxf(fmaxf(sacc[1][0], sacc[1][1]), fmaxf(sacc[1][2], sacc[1][3])));
          tm = fmaxf(tm, __shfl_xor(tm, 16));
          tm = fmaxf(tm, __shfl_xor(tm, 32));
          mrun = tm;
#pragma unroll
          for (int n = 0; n < 2; ++n)
#pragma unroll
            for (int r = 0; r < 4; ++r) sacc[n][r] -= mrun;   // -3e38-(-3e38)=0 ok
        }

        // ---- exp + lane-partial sum (no cross-lane ops)
        float rs = 0.f;
#pragma unroll
        for (int n = 0; n < 2; ++n) {
          float p0 = fexp2(sacc[n][0]);
          float p1 = fexp2(sacc[n][1]);
          float p2 = fexp2(sacc[n][2]);
          float p3 = fexp2(sacc[n][3]);
          rs += (p0 + p1) + (p2 + p3);
          uint2 wv;
          wv.x = cvt_pk_bf16(p0, p1);
          wv.y = cvt_pk_bf16(p2, p3);
          *(uint2*)(pw + pso[n]) = wv;
        }
        lrunp += rs;

        // ---- PV: O^T += V * P   (oacc[dn]: d = dn*16+lh*4+r, q = l15)
        bf16x8 pf = *(const bf16x8*)(pw + lb);
        __builtin_amdgcn_s_setprio(1);
#pragma unroll
        for (int dn = 0; dn < 4; ++dn) {
          bf16x8 vf = *(const bf16x8*)(vb + dn * 512 + lb);
          oacc[dn] = __builtin_amdgcn_mfma_f32_16x16x32_bf16(vf, pf, oacc[dn], 0, 0, 0);
        }
        __builtin_amdgcn_s_setprio(0);

        asm volatile("s_waitcnt vmcnt(0)" ::: "memory");
        __syncthreads();
      }
    }

    // ---- epilogue: reduce lane-partial l, store partial O + (m,l) ----
    {
      float lr = lrunp;
      lr += __shfl_xor(lr, 16);
      lr += __shfl_xor(lr, 32);

      if (kt0 < kt1) {
        float inv = 1.f / lr;
        u16* scr = pw;                       // 1KB wave scratch, values < 64 elems apart
#pragma unroll
        for (int dn = 0; dn < 4; ++dn) {
          int d0 = dn * 16 + lh * 4;
          uint2 wv;
          wv.x = cvt_pk_bf16(oacc[dn][0] * inv, oacc[dn][1] * inv);
          wv.y = cvt_pk_bf16(oacc[dn][2] * inv, oacc[dn][3] * inv);
          // bounce via Ks[0] region per wave: 16 q rows x 64 d
          *(uint2*)(&Ks[0][wave * 1024] + l15 * 64 + ((d0 + l15 * 8) & 63)) = wv;
        }
        (void)scr;
        asm volatile("s_waitcnt lgkmcnt(0)" ::: "memory");
        __builtin_amdgcn_sched_barrier(0);
        const int q  = lane >> 2;            // 16 rows x 4 d-chunks of 16
        const int dc = (lane & 3) * 16;
#pragma unroll
        for (int half = 0; half < 2; ++half) {
          int ds = dc + half * 8;
          i32x4 v = *(const i32x4*)(&Ks[0][wave * 1024] + q * 64 + ((ds + q * 8) & 63));
          *(i32x4*)(Og + (size_t)(qw0 + q) * DM + h * HD + ds) = v;
        }
      }
      if (lh == 0) {                         // per-q stats (m log2-domain, l)
        float2 s; s.x = mrun; s.y = lr;
        lmb[((size_t)g * NH + h) * TSEQ + qgl] = s;
      }
    }
    __syncthreads();                         // Ks[0] scratch reuse across phases
  }
}

// ---------------- merge the four kv-group partials ----------------
// O[q][h*64+d] = sum_g a_g * O_g,  a_g = 2^(m_g - m) * l_g / sum
__global__ void merge_o(const u16* __restrict__ Op012, const u16* __restrict__ Op3,
                        const float2* __restrict__ lmb, u16* __restrict__ Ob) {
  int i = blockIdx.x * 256 + threadIdx.x;    // [0, TSEQ*DM/8)
  int q  = i >> 7;
  int c8 = (i & 127) * 8;
  int h  = c8 >> 6;
  float2 s0 = lmb[(size_t)h * TSEQ + q];
  float2 s1 = lmb[((size_t)NH + h) * TSEQ + q];
  float2 s2 = lmb[((size_t)2 * NH + h) * TSEQ + q];
  float2 s3 = lmb[((size_t)3 * NH + h) * TSEQ + q];
  float m  = fmaxf(fmaxf(s0.x, s1.x), fmaxf(s2.x, s3.x));
  float w0 = fexp2(s0.x - m) * s0.y;
  float w1 = fexp2(s1.x - m) * s1.y;
  float w2 = fexp2(s2.x - m) * s2.y;
  float w3 = fexp2(s3.x - m) * s3.y;
  float inv = 1.f / (w0 + w1 + w2 + w3);
  float a0 = w0 * inv, a1 = w1 * inv, a2 = w2 * inv, a3 = w3 * inv;
  size_t off = (size_t)q * DM + c8;
  i32x4 u0 = *(const i32x4*)(Op012 + off);
  i32x4 u1 = *(const i32x4*)(Op012 + (size_t)(TSEQ * DM) + off);
  i32x4 u2 = *(const i32x4*)(Op012 + 2 * (size_t)(TSEQ * DM) + off);
  i32x4 u3 = *(const i32x4*)(Op3 + off);
  const u16* p0 = (const u16*)&u0;
  const u16* p1 = (const u16*)&u1;
  const u16* p2 = (const u16*)&u2;
  const u16* p3 = (const u16*)&u3;
  union { u16 o[8]; i32x4 v; } r;
#pragma unroll
  for (int e = 0; e < 8; ++e)
    r.o[e] = f2bf(a0 * bf2f(p0[e]) + a1 * bf2f(p1[e]) +
                  a2 * bf2f(p2[e]) + a3 * bf2f(p3[e]));
  *(i32x4*)(Ob + off) = r.v;
}

extern "C" void kernel_launch(void* const* d_in, const int* in_sizes, int n_in,
                              void* d_out, int out_size, void* d_ws, size_t ws_size,
                              hipStream_t stream)
{
  const float* x     = (const float*)d_in[0];
  const float* wqkv  = (const float*)d_in[1];
  const float* wproj = (const float*)d_in[2];
  float* out = (float*)d_out;

  char* ws = (char*)d_ws;
  size_t off = 0;
  u16* xb   = (u16*)(ws + off); off += (size_t)TSEQ * DM * 2;
  u16* wqb  = (u16*)(ws + off); off += (size_t)NQKV * DM * 2;
  u16* wpb  = (u16*)(ws + off); off += (size_t)DM * DM * 2;
  u16* qkvb = (u16*)(ws + off); off += (size_t)TSEQ * NQKV * 2;
  u16* Qb   = (u16*)(ws + off); off += (size_t)NH * TSEQ * HD * 2;
  u16* Kb   = (u16*)(ws + off); off += (size_t)NH * TSEQ * HD * 2;
  u16* Vb   = (u16*)(ws + off); off += (size_t)NH * TSEQ * HD * 2;
  u16* Ob   = (u16*)(ws + off); off += (size_t)TSEQ * DM * 2;
  float* sT = (float*)(ws + off); off += (size_t)TSEQ * 32 * 4;
  float* cT = (float*)(ws + off); off += (size_t)TSEQ * 32 * 4;

  // kv-split partials alias DEAD buffers: g0-2 in qkvb (24MB, dead after
  // rope_reorg), g3 in xb (8MB, dead after gemm1), stats in wqb (dead after gemm1).
  u16*    Opart012 = qkvb;
  u16*    Opart3   = xb;
  float2* lmb      = (float2*)wqb;

  const int ncast = N4X + N4Q + N4P;
  cast3_kernel<<<(ncast + 255) / 256, 256, 0, stream>>>(x, xb, wqkv, wqb, wproj, wpb);
  rope_table<<<(TSEQ * 32) / 256, 256, 0, stream>>>(sT, cT);

  gemm_bt<1><<<dim3(NQKV / 128, TSEQ / 128), 256, 0, stream>>>(xb, wqb, qkvb, TSEQ, NQKV, DM);

  rope_reorg<<<(TSEQ * NH * 32) / 256, 256, 0, stream>>>(qkvb, sT, cT, Qb, Kb, Vb);

  fattn<<<NH * 128, 256, 0, stream>>>(Qb, Kb, Vb, Opart012, Opart3, lmb);

  merge_o<<<(TSEQ * DM / 8) / 256, 256, 0, stream>>>(Opart012, Opart3, lmb, Ob);

  gemm_bt<0><<<dim3(DM / 128, TSEQ / 128), 256, 0, stream>>>(Ob, wpb, out, TSEQ, DM, DM);
}

// Round 12
// 155.801 us; speedup vs baseline: 1.0721x; 1.0720x over previous
//
#include <hip/hip_runtime.h>
#include <hip/hip_bf16.h>
#include <stdint.h>

#define TSEQ 4096
#define DM   1024
#define NH   16
#define HD   64
#define NQKV 3072

typedef unsigned short u16;
typedef unsigned int   u32;
typedef __attribute__((ext_vector_type(8)))  short bf16x8;
typedef __attribute__((ext_vector_type(4)))  float f32x4;
typedef __attribute__((ext_vector_type(16))) float f32x16;
typedef __attribute__((ext_vector_type(4)))  int   i32x4;

static __device__ __forceinline__ u16 f2bf(float f) {
  u32 u = __float_as_uint(f);
  u32 r = (u + 0x7FFFu + ((u >> 16) & 1u)) >> 16;   // RNE
  return (u16)r;
}
static __device__ __forceinline__ float bf2f(u16 u) {
  return __uint_as_float(((u32)u) << 16);
}
static __device__ __forceinline__ u32 cvt_pk_bf16(float lo, float hi) {
  u32 r;
  asm("v_cvt_pk_bf16_f32 %0, %1, %2" : "=v"(r) : "v"(lo), "v"(hi));
  return r;
}
static __device__ __forceinline__ float fexp2(float x) {   // guaranteed v_exp_f32
  float r;
  asm("v_exp_f32 %0, %1" : "=v"(r) : "v"(x));
  return r;
}

#define GLL16(g, l) __builtin_amdgcn_global_load_lds( \
    (const __attribute__((address_space(1))) u32*)(g), \
    (__attribute__((address_space(3))) u32*)(l), 16, 0, 0)

// ---------------- fused cast fp32 -> bf16 for x, W_qkv, W_proj --------------
#define N4X  (TSEQ * DM / 4)
#define N4Q  (NQKV * DM / 4)
#define N4P  (DM * DM / 4)
__global__ void cast3_kernel(const float* __restrict__ x, u16* __restrict__ xo,
                             const float* __restrict__ wq, u16* __restrict__ wqo,
                             const float* __restrict__ wp, u16* __restrict__ wpo) {
  int i = blockIdx.x * 256 + threadIdx.x;
  const float* in; u16* out; int k;
  if (i < N4X)            { in = x;  out = xo;  k = i; }
  else if (i < N4X + N4Q) { in = wq; out = wqo; k = i - N4X; }
  else if (i < N4X + N4Q + N4P) { in = wp; out = wpo; k = i - N4X - N4Q; }
  else return;
  float4 v = ((const float4*)in)[k];
  ushort4 o;
  o.x = f2bf(v.x); o.y = f2bf(v.y); o.z = f2bf(v.z); o.w = f2bf(v.w);
  ((ushort4*)out)[k] = o;
}

// ---------------- RoPE sin/cos table [T][32] ----------------
__global__ void rope_table(float* __restrict__ sT, float* __restrict__ cT) {
  int i = blockIdx.x * 256 + threadIdx.x;   // t*32 + j
  int t = i >> 5, j = i & 31;
  float inv = exp2f((float)j * (-13.287712379549449f / 32.0f)); // 10000^(-j/32)
  float ang = (float)t * inv;
  sT[i] = sinf(ang);
  cT[i] = cosf(ang);
}

// ---------------- GEMM C[M,N] = A[M,K] * B[N,K]^T (bf16 in, fp32 acc) --------
template<int WRITE_BF16>
__global__ __launch_bounds__(256) void gemm_bt(const u16* __restrict__ A,
                                               const u16* __restrict__ B,
                                               void* __restrict__ Cout,
                                               int M, int N, int K)
{
  __shared__ __align__(16) u16 As[128 * 32];
  __shared__ __align__(16) u16 Bs[128 * 32];
  const int tid  = threadIdx.x;
  const int wave = tid >> 6, lane = tid & 63;
  const int l15  = lane & 15, lh = lane >> 4;
  const int wr   = wave >> 1, wc = wave & 1;

  const int nwg = gridDim.x * gridDim.y;
  int lin = blockIdx.y * gridDim.x + blockIdx.x;
  lin = (lin & 7) * (nwg >> 3) + (lin >> 3);          // nwg % 8 == 0
  const size_t bm = (size_t)(lin / gridDim.x);
  const size_t bn = (size_t)(lin % gridDim.x);

  f32x4 acc[4][4] = {};

  const u16* Ab = A + bm * 128 * (size_t)K;
  const u16* Bb = B + bn * 128 * (size_t)K;

  for (int k0 = 0; k0 < K; k0 += 32) {
    __syncthreads();
#pragma unroll
    for (int j = 0; j < 2; ++j) {
      const int ch = j * 4 + wave;            // 8 chunks of 1024B per tile
      const int e  = ch * 512 + lane * 8;     // element within tile (row-major [128][32])
      const int r  = e >> 5, c = e & 31;
      GLL16(Ab + (size_t)r * K + k0 + c, As + ch * 512);
      GLL16(Bb + (size_t)r * K + k0 + c, Bs + ch * 512);
    }
    asm volatile("s_waitcnt vmcnt(0)" ::: "memory");
    __syncthreads();

    bf16x8 af[4], bfr[4];
#pragma unroll
    for (int m = 0; m < 4; ++m)
      af[m] = *(const bf16x8*)(As + (wr * 64 + m * 16 + l15) * 32 + lh * 8);
#pragma unroll
    for (int n = 0; n < 4; ++n)
      bfr[n] = *(const bf16x8*)(Bs + (wc * 64 + n * 16 + l15) * 32 + lh * 8);
#pragma unroll
    for (int m = 0; m < 4; ++m)
#pragma unroll
      for (int n = 0; n < 4; ++n)
        acc[m][n] = __builtin_amdgcn_mfma_f32_16x16x32_bf16(af[m], bfr[n], acc[m][n], 0, 0, 0);
  }

#pragma unroll
  for (int m = 0; m < 4; ++m)
#pragma unroll
    for (int n = 0; n < 4; ++n)
#pragma unroll
      for (int r = 0; r < 4; ++r) {
        size_t row = bm * 128 + wr * 64 + m * 16 + lh * 4 + r;
        size_t col = bn * 128 + wc * 64 + n * 16 + l15;
        float v = acc[m][n][r];
        if (WRITE_BF16) ((u16*)Cout)[row * N + col] = f2bf(v);
        else            ((float*)Cout)[row * N + col] = v;
      }
}

// ---------------- RoPE + head-split into 32x32-MFMA-fragment layouts --------
// Q,K (A/B-frag per 32-t tile, 2048 elems):
//   idx = (h*128 + (t>>5))*2048 + (d>>4)*512 + ((d>>3)&1)*256 + (t&31)*8 + (d&7)
// V^T (A-frag per 32-kv tile, 2048 elems):
//   idx = (h*128 + (t>>5))*2048 + ((d>>5)*2 + ((t>>4)&1))*512 + ((t>>3)&1)*256
//         + (d&31)*8 + (t&7)
__global__ void rope_reorg(const u16* __restrict__ qkv,
                           const float* __restrict__ sT, const float* __restrict__ cT,
                           u16* __restrict__ Qo, u16* __restrict__ Ko, u16* __restrict__ Vo)
{
  int idx = blockIdx.x * 256 + threadIdx.x;   // (t*16 + h)*32 + j
  int j = idx & 31;
  int h = (idx >> 5) & 15;
  int t = idx >> 9;
  const float QSC = 0.125f * 1.4426950408889634f;  // 1/sqrt(64) * log2(e)
  float s = sT[t * 32 + j], c = cT[t * 32 + j];
  const u16* row = qkv + (size_t)t * NQKV + h * HD;
  float q1 = bf2f(row[j]),        q2 = bf2f(row[j + 32]);
  float k1 = bf2f(row[DM + j]),   k2 = bf2f(row[DM + j + 32]);
  float qa = (q1 * c - q2 * s) * QSC, qb2 = (q2 * c + q1 * s) * QSC;
  float ka = k1 * c - k2 * s,         kb2 = k2 * c + k1 * s;

  int d0 = j, d1 = j + 32;
  size_t tbase = ((size_t)h * 128 + (t >> 5)) * 2048;
  size_t iA = tbase + (size_t)(d0 >> 4) * 512 + ((d0 >> 3) & 1) * 256 + (t & 31) * 8 + (d0 & 7);
  size_t iB = tbase + (size_t)(d1 >> 4) * 512 + ((d1 >> 3) & 1) * 256 + (t & 31) * 8 + (d1 & 7);
  Qo[iA] = f2bf(qa);  Qo[iB] = f2bf(qb2);
  Ko[iA] = f2bf(ka);  Ko[iB] = f2bf(kb2);

  size_t vb0 = tbase + (size_t)((t >> 4) & 1) * 512 + ((t >> 3) & 1) * 256 + (t & 7);
  Vo[vb0 + (size_t)(d0 & 31) * 8]        = row[2 * DM + j];        // d<32: frag 0/1
  Vo[vb0 + 1024 + (size_t)(d1 & 31) * 8] = row[2 * DM + j + 32];   // d>=32: +2 frags
}

// ---------------- causal flash attention, 32x32 MFMA, KVBLK=32, G=4 ---------
// grid 1024 blocks (= exactly 4/CU) x 256 thr. Block: q-tile 128 rows (4 waves
// x 32), phases {qt=pr, 31-pr}; group g gets exactly qt+1 kv tiles -> EVERY
// block does exactly 33 steps. 16KB LDS (K/V dbuf only; P stays in registers
// via cvt_pk+permlane32_swap). S^T = mfma(K,Q) (q = lane&31), O^T = mfma(V,P).
// No max tracking: group-first-tile bias; merge weights kill masked rows.
__global__ __launch_bounds__(256, 4) void fattn(const u16* __restrict__ Qf,
                                                const u16* __restrict__ Kf,
                                                const u16* __restrict__ Vf,
                                                u16* __restrict__ Op0,
                                                u16* __restrict__ Op123,
                                                float2* __restrict__ lmb)
{
  __shared__ __align__(16) u16 smem[8192];   // [0,4096): K dbuf; [4096,8192): V dbuf

  const int bid = blockIdx.x;
  const int h   = bid & (NH - 1);            // h, h+8 share XCD (bid&7)
  const int g   = (bid >> 4) & 3;            // kv group
  const int pr  = bid >> 6;                  // 0..15
  const int tid = threadIdx.x;
  const int wave = tid >> 6, lane = tid & 63;
  const int l31 = lane & 31, hh = lane >> 5;
  const int lb  = lane * 8;                  // linear fragment offset (elems)

  const size_t hbase = (size_t)h * (TSEQ * HD);
  const u16* kg = Kf + hbase;
  const u16* vg = Vf + hbase;
  u16* const Og = g ? (Op123 + (size_t)(g - 1) * (TSEQ * DM)) : Op0;

  for (int ph = 0; ph < 2; ++ph) {
    const int qt  = ph ? (31 - pr) : pr;     // 128-row q-tile index
    const int q0  = qt * 128;
    const int per = qt + 1;                  // 32-kv tiles per group (exact)
    const int kt0 = g * per, kt1 = kt0 + per;
    const int qw0 = q0 + wave * 32;          // this wave's first q row
    const int qgl = qw0 + l31;               // this lane's q row (global)

    f32x16 oacc0 = {}, oacc1 = {};
    float mrun = 0.f, lrunp = 0.f;           // LANE-PARTIAL l

    // Q fragments (B-operand), 4 k-chunks of 16 d
    bf16x8 qf[4];
    {
      const u16* qp = Qf + hbase + (size_t)(qt * 4 + wave) * 2048;
#pragma unroll
      for (int kc = 0; kc < 4; ++kc)
        qf[kc] = *(const bf16x8*)(qp + kc * 512 + lb);
    }

    // prologue: stage tile kt0 -> buf 0
    GLL16(kg + (size_t)kt0 * 2048 + tid * 8, smem + tid * 8);
    GLL16(vg + (size_t)kt0 * 2048 + tid * 8, smem + 4096 + tid * 8);
    asm volatile("s_waitcnt vmcnt(0)" ::: "memory");
    __syncthreads();

    for (int kt = kt0; kt < kt1; ++kt) {
      const int cur = (kt - kt0) & 1;
      if (kt + 1 < kt1) {                    // stage next tile during compute
        GLL16(kg + (size_t)(kt + 1) * 2048 + tid * 8, smem + (cur ^ 1) * 2048 + tid * 8);
        GLL16(vg + (size_t)(kt + 1) * 2048 + tid * 8, smem + 4096 + (cur ^ 1) * 2048 + tid * 8);
      }
      const u16* kb = smem + cur * 2048;
      const u16* vb = smem + 4096 + cur * 2048;
      const int kv0 = kt * 32;

      // ---- S^T = mfma(K,Q), C-init = -mrun (kt>kt0): exp input ready
      const float mz = (kt == kt0) ? 0.f : -mrun;
      f32x16 s0;
      __builtin_amdgcn_s_setprio(1);
      {
        f32x16 z;
#pragma unroll
        for (int i2 = 0; i2 < 16; ++i2) z[i2] = mz;
        bf16x8 kf0 = *(const bf16x8*)(kb + lb);
        s0 = __builtin_amdgcn_mfma_f32_32x32x16_bf16(kf0, qf[0], z, 0, 0, 0);
      }
#pragma unroll
      for (int kc = 1; kc < 4; ++kc) {
        bf16x8 kf = *(const bf16x8*)(kb + kc * 512 + lb);
        s0 = __builtin_amdgcn_mfma_f32_32x32x16_bf16(kf, qf[kc], s0, 0, 0, 0);
      }
      __builtin_amdgcn_s_setprio(0);

      if (kv0 + 31 > qw0) {                  // wave-uniform: diagonal-ish tile
#pragma unroll
        for (int r = 0; r < 16; ++r) {
          int kvr = kv0 + (r & 3) + 8 * (r >> 2) + 4 * hh;
          if (kvr > qgl) s0[r] = -3.0e38f;
        }
      }

      if (kt == kt0) {                       // group-first tile: row max bias
        float tm = -3.0e38f;
#pragma unroll
        for (int r = 0; r < 16; ++r) tm = fmaxf(tm, s0[r]);
        tm = fmaxf(tm, __shfl_xor(tm, 32));
        mrun = tm;
#pragma unroll
        for (int r = 0; r < 16; ++r) s0[r] -= mrun;   // -3e38-(-3e38)=0 ok
      }

      // ---- exp + lane-partial sum (no cross-lane ops)
      float rs = 0.f;
#pragma unroll
      for (int r = 0; r < 16; ++r) {
        s0[r] = fexp2(s0[r]);
        rs += s0[r];
      }
      lrunp += rs;

      // ---- P fragments in-register: cvt_pk pairs + permlane32_swap (R3-verified)
      bf16x8 pf[2];
#pragma unroll
      for (int kc = 0; kc < 2; ++kc) {
        const int e = 8 * kc;
        u32 Xa = cvt_pk_bf16(s0[e + 0], s0[e + 1]);
        u32 Xb = cvt_pk_bf16(s0[e + 2], s0[e + 3]);
        u32 Ya = cvt_pk_bf16(s0[e + 4], s0[e + 5]);
        u32 Yb = cvt_pk_bf16(s0[e + 6], s0[e + 7]);
        asm volatile("v_permlane32_swap_b32 %0, %1" : "+v"(Xa), "+v"(Ya));
        asm volatile("v_permlane32_swap_b32 %0, %1" : "+v"(Xb), "+v"(Yb));
        union { u32 u[4]; bf16x8 v; } pu;
        pu.u[0] = Xa; pu.u[1] = Xb; pu.u[2] = Ya; pu.u[3] = Yb;
        pf[kc] = pu.v;
      }

      // ---- PV: O^T += V * P   (oacc_m: d = m*32 + rowmap, q = l31)
      __builtin_amdgcn_s_setprio(1);
#pragma unroll
      for (int s2 = 0; s2 < 2; ++s2) {
        bf16x8 v0 = *(const bf16x8*)(vb + (0 * 2 + s2) * 512 + lb);
        bf16x8 v1 = *(const bf16x8*)(vb + (1 * 2 + s2) * 512 + lb);
        oacc0 = __builtin_amdgcn_mfma_f32_32x32x16_bf16(v0, pf[s2], oacc0, 0, 0, 0);
        oacc1 = __builtin_amdgcn_mfma_f32_32x32x16_bf16(v1, pf[s2], oacc1, 0, 0, 0);
      }
      __builtin_amdgcn_s_setprio(0);

      asm volatile("s_waitcnt vmcnt(0)" ::: "memory");
      __syncthreads();
    }

    // ---- epilogue: reduce lane-partial l, normalize, LDS bounce, store -----
    {
      float lr = lrunp + __shfl_xor(lrunp, 32);
      float inv = 1.f / lr;
      u16* scr = smem + wave * 2048;         // wave-private 4KB (K/V bufs done)
#pragma unroll
      for (int dt = 0; dt < 2; ++dt)
#pragma unroll
        for (int rq = 0; rq < 4; ++rq) {
          float v0 = (dt ? oacc1[4 * rq + 0] : oacc0[4 * rq + 0]) * inv;
          float v1 = (dt ? oacc1[4 * rq + 1] : oacc0[4 * rq + 1]) * inv;
          float v2 = (dt ? oacc1[4 * rq + 2] : oacc0[4 * rq + 2]) * inv;
          float v3 = (dt ? oacc1[4 * rq + 3] : oacc0[4 * rq + 3]) * inv;
          uint2 wv;
          wv.x = cvt_pk_bf16(v0, v1);
          wv.y = cvt_pk_bf16(v2, v3);
          int g2 = 4 * dt + rq;
          *(uint2*)(scr + l31 * 64 + ((g2 ^ (l31 & 7)) * 8) + 4 * hh) = wv;
        }
      asm volatile("s_waitcnt lgkmcnt(0)" ::: "memory");
      __builtin_amdgcn_sched_barrier(0);
      const int q  = lane >> 1;              // 32 rows x 2 d-halves
      const int dh = lane & 1;
#pragma unroll
      for (int c2 = 0; c2 < 4; ++c2) {
        int gg = dh * 4 + c2;
        i32x4 v = *(const i32x4*)(scr + q * 64 + ((gg ^ (q & 7)) * 8));
        *(i32x4*)(Og + (size_t)(qw0 + q) * DM + h * HD + dh * 32 + c2 * 8) = v;
      }
      if (hh == 0)                           // per-q stats (m log2-domain, l)
        lmb[((size_t)g * NH + h) * TSEQ + qgl] = make_float2(mrun, lr);
    }
    __syncthreads();                         // smem reused by next phase
  }
}

// ---------------- merge the four kv-group partials ----------------
// O[q][h*64+d] = sum_g a_g * O_g,  a_g = 2^(m_g - m) * l_g / sum
__global__ void merge_o(const u16* __restrict__ Op0, const u16* __restrict__ Op123,
                        const float2* __restrict__ lmb, u16* __restrict__ Ob) {
  int i = blockIdx.x * 256 + threadIdx.x;    // [0, TSEQ*DM/8)
  int q  = i >> 7;
  int c8 = (i & 127) * 8;
  int h  = c8 >> 6;
  float2 s0 = lmb[(size_t)h * TSEQ + q];
  float2 s1 = lmb[((size_t)NH + h) * TSEQ + q];
  float2 s2 = lmb[((size_t)2 * NH + h) * TSEQ + q];
  float2 s3 = lmb[((size_t)3 * NH + h) * TSEQ + q];
  float m  = fmaxf(fmaxf(s0.x, s1.x), fmaxf(s2.x, s3.x));
  float w0 = fexp2(s0.x - m) * s0.y;
  float w1 = fexp2(s1.x - m) * s1.y;
  float w2 = fexp2(s2.x - m) * s2.y;
  float w3 = fexp2(s3.x - m) * s3.y;
  float inv = 1.f / (w0 + w1 + w2 + w3);
  float a0 = w0 * inv, a1 = w1 * inv, a2 = w2 * inv, a3 = w3 * inv;
  size_t off = (size_t)q * DM + c8;
  i32x4 u0 = *(const i32x4*)(Op0 + off);
  i32x4 u1 = *(const i32x4*)(Op123 + off);
  i32x4 u2 = *(const i32x4*)(Op123 + (size_t)(TSEQ * DM) + off);
  i32x4 u3 = *(const i32x4*)(Op123 + 2 * (size_t)(TSEQ * DM) + off);
  const u16* p0 = (const u16*)&u0;
  const u16* p1 = (const u16*)&u1;
  const u16* p2 = (const u16*)&u2;
  const u16* p3 = (const u16*)&u3;
  union { u16 o[8]; i32x4 v; } r;
#pragma unroll
  for (int e = 0; e < 8; ++e)
    r.o[e] = f2bf(a0 * bf2f(p0[e]) + a1 * bf2f(p1[e]) +
                  a2 * bf2f(p2[e]) + a3 * bf2f(p3[e]));
  *(i32x4*)(Ob + off) = r.v;
}

extern "C" void kernel_launch(void* const* d_in, const int* in_sizes, int n_in,
                              void* d_out, int out_size, void* d_ws, size_t ws_size,
                              hipStream_t stream)
{
  const float* x     = (const float*)d_in[0];
  const float* wqkv  = (const float*)d_in[1];
  const float* wproj = (const float*)d_in[2];
  float* out = (float*)d_out;

  char* ws = (char*)d_ws;
  size_t off = 0;
  u16* xb   = (u16*)(ws + off); off += (size_t)TSEQ * DM * 2;
  u16* wqb  = (u16*)(ws + off); off += (size_t)NQKV * DM * 2;
  u16* wpb  = (u16*)(ws + off); off += (size_t)DM * DM * 2;
  u16* qkvb = (u16*)(ws + off); off += (size_t)TSEQ * NQKV * 2;
  u16* Qb   = (u16*)(ws + off); off += (size_t)NH * TSEQ * HD * 2;
  u16* Kb   = (u16*)(ws + off); off += (size_t)NH * TSEQ * HD * 2;
  u16* Vb   = (u16*)(ws + off); off += (size_t)NH * TSEQ * HD * 2;
  u16* Ob   = (u16*)(ws + off); off += (size_t)TSEQ * DM * 2;
  float* sT = (float*)(ws + off); off += (size_t)TSEQ * 32 * 4;
  float* cT = (float*)(ws + off); off += (size_t)TSEQ * 32 * 4;

  // kv-split partials: g0 writes Ob directly; g1-3 alias qkvb (24MB, dead
  // after rope_reorg); stats alias wqb (2MB, dead after gemm1).
  u16*    Op123 = qkvb;
  float2* lmb   = (float2*)wqb;

  const int ncast = N4X + N4Q + N4P;
  cast3_kernel<<<(ncast + 255) / 256, 256, 0, stream>>>(x, xb, wqkv, wqb, wproj, wpb);
  rope_table<<<(TSEQ * 32) / 256, 256, 0, stream>>>(sT, cT);

  gemm_bt<1><<<dim3(NQKV / 128, TSEQ / 128), 256, 0, stream>>>(xb, wqb, qkvb, TSEQ, NQKV, DM);

  rope_reorg<<<(TSEQ * NH * 32) / 256, 256, 0, stream>>>(qkvb, sT, cT, Qb, Kb, Vb);

  fattn<<<NH * 64, 256, 0, stream>>>(Qb, Kb, Vb, Ob, Op123, lmb);

  merge_o<<<(TSEQ * DM / 8) / 256, 256, 0, stream>>>(Ob, Op123, lmb, Ob);

  gemm_bt<0><<<dim3(DM / 128, TSEQ / 128), 256, 0, stream>>>(Ob, wpb, out, TSEQ, DM, DM);
}

// Round 13
// 151.775 us; speedup vs baseline: 1.1006x; 1.0265x over previous
//
#include <hip/hip_runtime.h>
#include <hip/hip_bf16.h>
#include <stdint.h>

#define TSEQ 4096
#define DM   1024
#define NH   16
#define HD   64
#define NQKV 3072

typedef unsigned short u16;
typedef unsigned int   u32;
typedef __attribute__((ext_vector_type(8)))  short bf16x8;
typedef __attribute__((ext_vector_type(4)))  float f32x4;
typedef __attribute__((ext_vector_type(16))) float f32x16;
typedef __attribute__((ext_vector_type(4)))  int   i32x4;

static __device__ __forceinline__ u16 f2bf(float f) {
  u32 u = __float_as_uint(f);
  u32 r = (u + 0x7FFFu + ((u >> 16) & 1u)) >> 16;   // RNE
  return (u16)r;
}
static __device__ __forceinline__ float bf2f(u16 u) {
  return __uint_as_float(((u32)u) << 16);
}
static __device__ __forceinline__ u32 cvt_pk_bf16(float lo, float hi) {
  u32 r;
  asm("v_cvt_pk_bf16_f32 %0, %1, %2" : "=v"(r) : "v"(lo), "v"(hi));
  return r;
}
static __device__ __forceinline__ float fexp2(float x) {   // guaranteed v_exp_f32
  float r;
  asm("v_exp_f32 %0, %1" : "=v"(r) : "v"(x));
  return r;
}

#define GLL16(g, l) __builtin_amdgcn_global_load_lds( \
    (const __attribute__((address_space(1))) u32*)(g), \
    (__attribute__((address_space(3))) u32*)(l), 16, 0, 0)

// ---------------- fused cast fp32 -> bf16 for x, W_qkv, W_proj --------------
#define N4X  (TSEQ * DM / 4)
#define N4Q  (NQKV * DM / 4)
#define N4P  (DM * DM / 4)
__global__ void cast3_kernel(const float* __restrict__ x, u16* __restrict__ xo,
                             const float* __restrict__ wq, u16* __restrict__ wqo,
                             const float* __restrict__ wp, u16* __restrict__ wpo) {
  int i = blockIdx.x * 256 + threadIdx.x;
  const float* in; u16* out; int k;
  if (i < N4X)            { in = x;  out = xo;  k = i; }
  else if (i < N4X + N4Q) { in = wq; out = wqo; k = i - N4X; }
  else if (i < N4X + N4Q + N4P) { in = wp; out = wpo; k = i - N4X - N4Q; }
  else return;
  float4 v = ((const float4*)in)[k];
  ushort4 o;
  o.x = f2bf(v.x); o.y = f2bf(v.y); o.z = f2bf(v.z); o.w = f2bf(v.w);
  ((ushort4*)out)[k] = o;
}

// ---------------- RoPE sin/cos table [T][32] ----------------
__global__ void rope_table(float* __restrict__ sT, float* __restrict__ cT) {
  int i = blockIdx.x * 256 + threadIdx.x;   // t*32 + j
  int t = i >> 5, j = i & 31;
  float inv = exp2f((float)j * (-13.287712379549449f / 32.0f)); // 10000^(-j/32)
  float ang = (float)t * inv;
  sT[i] = sinf(ang);
  cT[i] = cosf(ang);
}

// ---------------- GEMM C[M,N] = A[M,K] * B[N,K]^T (bf16 in, fp32 acc) --------
// 2-phase double-buffered staging (T3-minimum): issue STAGE(k+1) BEFORE the
// ds_read+MFMA of tile k; ONE vmcnt(0)+barrier per K-step. LDS 32KB.
template<int WRITE_BF16>
__global__ __launch_bounds__(256) void gemm_bt(const u16* __restrict__ A,
                                               const u16* __restrict__ B,
                                               void* __restrict__ Cout,
                                               int M, int N, int K)
{
  __shared__ __align__(16) u16 As[2][128 * 32];
  __shared__ __align__(16) u16 Bs[2][128 * 32];
  const int tid  = threadIdx.x;
  const int wave = tid >> 6, lane = tid & 63;
  const int l15  = lane & 15, lh = lane >> 4;
  const int wr   = wave >> 1, wc = wave & 1;

  const int nwg = gridDim.x * gridDim.y;
  int lin = blockIdx.y * gridDim.x + blockIdx.x;
  lin = (lin & 7) * (nwg >> 3) + (lin >> 3);          // nwg % 8 == 0
  const size_t bm = (size_t)(lin / gridDim.x);
  const size_t bn = (size_t)(lin % gridDim.x);

  f32x4 acc[4][4] = {};

  const u16* Ab = A + bm * 128 * (size_t)K;
  const u16* Bb = B + bn * 128 * (size_t)K;

  // staging chunk coords (row-major [128][32] tile, 8 chunks of 1024B each)
  const int ch0 = wave,     e0 = ch0 * 512 + lane * 8, r0 = e0 >> 5, c0 = e0 & 31;
  const int ch1 = 4 + wave, e1 = ch1 * 512 + lane * 8, r1 = e1 >> 5, c1 = e1 & 31;

  // prologue: stage k=0 into buf 0
  GLL16(Ab + (size_t)r0 * K + c0, &As[0][ch0 * 512]);
  GLL16(Ab + (size_t)r1 * K + c1, &As[0][ch1 * 512]);
  GLL16(Bb + (size_t)r0 * K + c0, &Bs[0][ch0 * 512]);
  GLL16(Bb + (size_t)r1 * K + c1, &Bs[0][ch1 * 512]);
  asm volatile("s_waitcnt vmcnt(0)" ::: "memory");
  __syncthreads();

  int cur = 0;
  for (int k0 = 0; k0 < K; k0 += 32, cur ^= 1) {
    if (k0 + 32 < K) {                      // issue next-tile loads (async)
      const int kn = k0 + 32;
      GLL16(Ab + (size_t)r0 * K + kn + c0, &As[cur ^ 1][ch0 * 512]);
      GLL16(Ab + (size_t)r1 * K + kn + c1, &As[cur ^ 1][ch1 * 512]);
      GLL16(Bb + (size_t)r0 * K + kn + c0, &Bs[cur ^ 1][ch0 * 512]);
      GLL16(Bb + (size_t)r1 * K + kn + c1, &Bs[cur ^ 1][ch1 * 512]);
    }

    bf16x8 af[4], bfr[4];
#pragma unroll
    for (int m = 0; m < 4; ++m)
      af[m] = *(const bf16x8*)(&As[cur][(wr * 64 + m * 16 + l15) * 32 + lh * 8]);
#pragma unroll
    for (int n = 0; n < 4; ++n)
      bfr[n] = *(const bf16x8*)(&Bs[cur][(wc * 64 + n * 16 + l15) * 32 + lh * 8]);
    __builtin_amdgcn_s_setprio(1);
#pragma unroll
    for (int m = 0; m < 4; ++m)
#pragma unroll
      for (int n = 0; n < 4; ++n)
        acc[m][n] = __builtin_amdgcn_mfma_f32_16x16x32_bf16(af[m], bfr[n], acc[m][n], 0, 0, 0);
    __builtin_amdgcn_s_setprio(0);

    asm volatile("s_waitcnt vmcnt(0)" ::: "memory");
    __syncthreads();
  }

#pragma unroll
  for (int m = 0; m < 4; ++m)
#pragma unroll
    for (int n = 0; n < 4; ++n)
#pragma unroll
      for (int r = 0; r < 4; ++r) {
        size_t row = bm * 128 + wr * 64 + m * 16 + lh * 4 + r;
        size_t col = bn * 128 + wc * 64 + n * 16 + l15;
        float v = acc[m][n][r];
        if (WRITE_BF16) ((u16*)Cout)[row * N + col] = f2bf(v);
        else            ((float*)Cout)[row * N + col] = v;
      }
}

// ---------------- RoPE + head-split into 32x32-MFMA-fragment layouts --------
// Q,K (A/B-frag per 32-t tile, 2048 elems):
//   idx = (h*128 + (t>>5))*2048 + (d>>4)*512 + ((d>>3)&1)*256 + (t&31)*8 + (d&7)
// V^T (A-frag per 32-kv tile, 2048 elems):
//   idx = (h*128 + (t>>5))*2048 + ((d>>5)*2 + ((t>>4)&1))*512 + ((t>>3)&1)*256
//         + (d&31)*8 + (t&7)
__global__ void rope_reorg(const u16* __restrict__ qkv,
                           const float* __restrict__ sT, const float* __restrict__ cT,
                           u16* __restrict__ Qo, u16* __restrict__ Ko, u16* __restrict__ Vo)
{
  int idx = blockIdx.x * 256 + threadIdx.x;   // (t*16 + h)*32 + j
  int j = idx & 31;
  int h = (idx >> 5) & 15;
  int t = idx >> 9;
  const float QSC = 0.125f * 1.4426950408889634f;  // 1/sqrt(64) * log2(e)
  float s = sT[t * 32 + j], c = cT[t * 32 + j];
  const u16* row = qkv + (size_t)t * NQKV + h * HD;
  float q1 = bf2f(row[j]),        q2 = bf2f(row[j + 32]);
  float k1 = bf2f(row[DM + j]),   k2 = bf2f(row[DM + j + 32]);
  float qa = (q1 * c - q2 * s) * QSC, qb2 = (q2 * c + q1 * s) * QSC;
  float ka = k1 * c - k2 * s,         kb2 = k2 * c + k1 * s;

  int d0 = j, d1 = j + 32;
  size_t tbase = ((size_t)h * 128 + (t >> 5)) * 2048;
  size_t iA = tbase + (size_t)(d0 >> 4) * 512 + ((d0 >> 3) & 1) * 256 + (t & 31) * 8 + (d0 & 7);
  size_t iB = tbase + (size_t)(d1 >> 4) * 512 + ((d1 >> 3) & 1) * 256 + (t & 31) * 8 + (d1 & 7);
  Qo[iA] = f2bf(qa);  Qo[iB] = f2bf(qb2);
  Ko[iA] = f2bf(ka);  Ko[iB] = f2bf(kb2);

  size_t vb0 = tbase + (size_t)((t >> 4) & 1) * 512 + ((t >> 3) & 1) * 256 + (t & 7);
  Vo[vb0 + (size_t)(d0 & 31) * 8]        = row[2 * DM + j];        // d<32: frag 0/1
  Vo[vb0 + 1024 + (size_t)(d1 & 31) * 8] = row[2 * DM + j + 32];   // d>=32: +2 frags
}

// ---------------- causal flash attention, 32x32 MFMA, KVBLK=32, G=4 ---------
// grid 1024 blocks (= exactly 4/CU) x 256 thr. Block: q-tile 128 rows (4 waves
// x 32), phases {qt=pr, 31-pr}; group g gets exactly qt+1 kv tiles -> EVERY
// block does exactly 33 steps. 16KB LDS (K/V dbuf only; P stays in registers
// via cvt_pk+permlane32_swap). S^T = mfma(K,Q) (q = lane&31), O^T = mfma(V,P).
// No max tracking: group-first-tile bias; merge weights kill masked rows.
__global__ __launch_bounds__(256, 4) void fattn(const u16* __restrict__ Qf,
                                                const u16* __restrict__ Kf,
                                                const u16* __restrict__ Vf,
                                                u16* __restrict__ Op0,
                                                u16* __restrict__ Op123,
                                                float2* __restrict__ lmb)
{
  __shared__ __align__(16) u16 smem[8192];   // [0,4096): K dbuf; [4096,8192): V dbuf

  const int bid = blockIdx.x;
  const int h   = bid & (NH - 1);            // h, h+8 share XCD (bid&7)
  const int g   = (bid >> 4) & 3;            // kv group
  const int pr  = bid >> 6;                  // 0..15
  const int tid = threadIdx.x;
  const int wave = tid >> 6, lane = tid & 63;
  const int l31 = lane & 31, hh = lane >> 5;
  const int lb  = lane * 8;                  // linear fragment offset (elems)

  const size_t hbase = (size_t)h * (TSEQ * HD);
  const u16* kg = Kf + hbase;
  const u16* vg = Vf + hbase;
  u16* const Og = g ? (Op123 + (size_t)(g - 1) * (TSEQ * DM)) : Op0;

  for (int ph = 0; ph < 2; ++ph) {
    const int qt  = ph ? (31 - pr) : pr;     // 128-row q-tile index
    const int q0  = qt * 128;
    const int per = qt + 1;                  // 32-kv tiles per group (exact)
    const int kt0 = g * per, kt1 = kt0 + per;
    const int qw0 = q0 + wave * 32;          // this wave's first q row
    const int qgl = qw0 + l31;               // this lane's q row (global)

    f32x16 oacc0 = {}, oacc1 = {};
    float mrun = 0.f, lrunp = 0.f;           // LANE-PARTIAL l

    // Q fragments (B-operand), 4 k-chunks of 16 d
    bf16x8 qf[4];
    {
      const u16* qp = Qf + hbase + (size_t)(qt * 4 + wave) * 2048;
#pragma unroll
      for (int kc = 0; kc < 4; ++kc)
        qf[kc] = *(const bf16x8*)(qp + kc * 512 + lb);
    }

    // prologue: stage tile kt0 -> buf 0
    GLL16(kg + (size_t)kt0 * 2048 + tid * 8, smem + tid * 8);
    GLL16(vg + (size_t)kt0 * 2048 + tid * 8, smem + 4096 + tid * 8);
    asm volatile("s_waitcnt vmcnt(0)" ::: "memory");
    __syncthreads();

    for (int kt = kt0; kt < kt1; ++kt) {
      const int cur = (kt - kt0) & 1;
      if (kt + 1 < kt1) {                    // stage next tile during compute
        GLL16(kg + (size_t)(kt + 1) * 2048 + tid * 8, smem + (cur ^ 1) * 2048 + tid * 8);
        GLL16(vg + (size_t)(kt + 1) * 2048 + tid * 8, smem + 4096 + (cur ^ 1) * 2048 + tid * 8);
      }
      const u16* kb = smem + cur * 2048;
      const u16* vb = smem + 4096 + cur * 2048;
      const int kv0 = kt * 32;

      // ---- S^T = mfma(K,Q), C-init = -mrun (kt>kt0): exp input ready
      const float mz = (kt == kt0) ? 0.f : -mrun;
      f32x16 s0;
      __builtin_amdgcn_s_setprio(1);
      {
        f32x16 z;
#pragma unroll
        for (int i2 = 0; i2 < 16; ++i2) z[i2] = mz;
        bf16x8 kf0 = *(const bf16x8*)(kb + lb);
        s0 = __builtin_amdgcn_mfma_f32_32x32x16_bf16(kf0, qf[0], z, 0, 0, 0);
      }
#pragma unroll
      for (int kc = 1; kc < 4; ++kc) {
        bf16x8 kf = *(const bf16x8*)(kb + kc * 512 + lb);
        s0 = __builtin_amdgcn_mfma_f32_32x32x16_bf16(kf, qf[kc], s0, 0, 0, 0);
      }
      __builtin_amdgcn_s_setprio(0);

      if (kv0 + 31 > qw0) {                  // wave-uniform: diagonal-ish tile
#pragma unroll
        for (int r = 0; r < 16; ++r) {
          int kvr = kv0 + (r & 3) + 8 * (r >> 2) + 4 * hh;
          if (kvr > qgl) s0[r] = -3.0e38f;
        }
      }

      if (kt == kt0) {                       // group-first tile: row max bias
        float tm = -3.0e38f;
#pragma unroll
        for (int r = 0; r < 16; ++r) tm = fmaxf(tm, s0[r]);
        tm = fmaxf(tm, __shfl_xor(tm, 32));
        mrun = tm;
#pragma unroll
        for (int r = 0; r < 16; ++r) s0[r] -= mrun;   // -3e38-(-3e38)=0 ok
      }

      // ---- exp + lane-partial sum (no cross-lane ops)
      float rs = 0.f;
#pragma unroll
      for (int r = 0; r < 16; ++r) {
        s0[r] = fexp2(s0[r]);
        rs += s0[r];
      }
      lrunp += rs;

      // ---- P fragments in-register: cvt_pk pairs + permlane32_swap (R3-verified)
      bf16x8 pf[2];
#pragma unroll
      for (int kc = 0; kc < 2; ++kc) {
        const int e = 8 * kc;
        u32 Xa = cvt_pk_bf16(s0[e + 0], s0[e + 1]);
        u32 Xb = cvt_pk_bf16(s0[e + 2], s0[e + 3]);
        u32 Ya = cvt_pk_bf16(s0[e + 4], s0[e + 5]);
        u32 Yb = cvt_pk_bf16(s0[e + 6], s0[e + 7]);
        asm volatile("v_permlane32_swap_b32 %0, %1" : "+v"(Xa), "+v"(Ya));
        asm volatile("v_permlane32_swap_b32 %0, %1" : "+v"(Xb), "+v"(Yb));
        union { u32 u[4]; bf16x8 v; } pu;
        pu.u[0] = Xa; pu.u[1] = Xb; pu.u[2] = Ya; pu.u[3] = Yb;
        pf[kc] = pu.v;
      }

      // ---- PV: O^T += V * P   (oacc_m: d = m*32 + rowmap, q = l31)
      __builtin_amdgcn_s_setprio(1);
#pragma unroll
      for (int s2 = 0; s2 < 2; ++s2) {
        bf16x8 v0 = *(const bf16x8*)(vb + (0 * 2 + s2) * 512 + lb);
        bf16x8 v1 = *(const bf16x8*)(vb + (1 * 2 + s2) * 512 + lb);
        oacc0 = __builtin_amdgcn_mfma_f32_32x32x16_bf16(v0, pf[s2], oacc0, 0, 0, 0);
        oacc1 = __builtin_amdgcn_mfma_f32_32x32x16_bf16(v1, pf[s2], oacc1, 0, 0, 0);
      }
      __builtin_amdgcn_s_setprio(0);

      asm volatile("s_waitcnt vmcnt(0)" ::: "memory");
      __syncthreads();
    }

    // ---- epilogue: reduce lane-partial l, normalize, LDS bounce, store -----
    {
      float lr = lrunp + __shfl_xor(lrunp, 32);
      float inv = 1.f / lr;
      u16* scr = smem + wave * 2048;         // wave-private 4KB (K/V bufs done)
#pragma unroll
      for (int dt = 0; dt < 2; ++dt)
#pragma unroll
        for (int rq = 0; rq < 4; ++rq) {
          float v0 = (dt ? oacc1[4 * rq + 0] : oacc0[4 * rq + 0]) * inv;
          float v1 = (dt ? oacc1[4 * rq + 1] : oacc0[4 * rq + 1]) * inv;
          float v2 = (dt ? oacc1[4 * rq + 2] : oacc0[4 * rq + 2]) * inv;
          float v3 = (dt ? oacc1[4 * rq + 3] : oacc0[4 * rq + 3]) * inv;
          uint2 wv;
          wv.x = cvt_pk_bf16(v0, v1);
          wv.y = cvt_pk_bf16(v2, v3);
          int g2 = 4 * dt + rq;
          *(uint2*)(scr + l31 * 64 + ((g2 ^ (l31 & 7)) * 8) + 4 * hh) = wv;
        }
      asm volatile("s_waitcnt lgkmcnt(0)" ::: "memory");
      __builtin_amdgcn_sched_barrier(0);
      const int q  = lane >> 1;              // 32 rows x 2 d-halves
      const int dh = lane & 1;
#pragma unroll
      for (int c2 = 0; c2 < 4; ++c2) {
        int gg = dh * 4 + c2;
        i32x4 v = *(const i32x4*)(scr + q * 64 + ((gg ^ (q & 7)) * 8));
        *(i32x4*)(Og + (size_t)(qw0 + q) * DM + h * HD + dh * 32 + c2 * 8) = v;
      }
      if (hh == 0)                           // per-q stats (m log2-domain, l)
        lmb[((size_t)g * NH + h) * TSEQ + qgl] = make_float2(mrun, lr);
    }
    __syncthreads();                         // smem reused by next phase
  }
}

// ---------------- merge the four kv-group partials ----------------
// O[q][h*64+d] = sum_g a_g * O_g,  a_g = 2^(m_g - m) * l_g / sum
__global__ void merge_o(const u16* __restrict__ Op0, const u16* __restrict__ Op123,
                        const float2* __restrict__ lmb, u16* __restrict__ Ob) {
  int i = blockIdx.x * 256 + threadIdx.x;    // [0, TSEQ*DM/8)
  int q  = i >> 7;
  int c8 = (i & 127) * 8;
  int h  = c8 >> 6;
  float2 s0 = lmb[(size_t)h * TSEQ + q];
  float2 s1 = lmb[((size_t)NH + h) * TSEQ + q];
  float2 s2 = lmb[((size_t)2 * NH + h) * TSEQ + q];
  float2 s3 = lmb[((size_t)3 * NH + h) * TSEQ + q];
  float m  = fmaxf(fmaxf(s0.x, s1.x), fmaxf(s2.x, s3.x));
  float w0 = fexp2(s0.x - m) * s0.y;
  float w1 = fexp2(s1.x - m) * s1.y;
  float w2 = fexp2(s2.x - m) * s2.y;
  float w3 = fexp2(s3.x - m) * s3.y;
  float inv = 1.f / (w0 + w1 + w2 + w3);
  float a0 = w0 * inv, a1 = w1 * inv, a2 = w2 * inv, a3 = w3 * inv;
  size_t off = (size_t)q * DM + c8;
  i32x4 u0 = *(const i32x4*)(Op0 + off);
  i32x4 u1 = *(const i32x4*)(Op123 + off);
  i32x4 u2 = *(const i32x4*)(Op123 + (size_t)(TSEQ * DM) + off);
  i32x4 u3 = *(const i32x4*)(Op123 + 2 * (size_t)(TSEQ * DM) + off);
  const u16* p0 = (const u16*)&u0;
  const u16* p1 = (const u16*)&u1;
  const u16* p2 = (const u16*)&u2;
  const u16* p3 = (const u16*)&u3;
  union { u16 o[8]; i32x4 v; } r;
#pragma unroll
  for (int e = 0; e < 8; ++e)
    r.o[e] = f2bf(a0 * bf2f(p0[e]) + a1 * bf2f(p1[e]) +
                  a2 * bf2f(p2[e]) + a3 * bf2f(p3[e]));
  *(i32x4*)(Ob + off) = r.v;
}

extern "C" void kernel_launch(void* const* d_in, const int* in_sizes, int n_in,
                              void* d_out, int out_size, void* d_ws, size_t ws_size,
                              hipStream_t stream)
{
  const float* x     = (const float*)d_in[0];
  const float* wqkv  = (const float*)d_in[1];
  const float* wproj = (const float*)d_in[2];
  float* out = (float*)d_out;

  char* ws = (char*)d_ws;
  size_t off = 0;
  u16* xb   = (u16*)(ws + off); off += (size_t)TSEQ * DM * 2;
  u16* wqb  = (u16*)(ws + off); off += (size_t)NQKV * DM * 2;
  u16* wpb  = (u16*)(ws + off); off += (size_t)DM * DM * 2;
  u16* qkvb = (u16*)(ws + off); off += (size_t)TSEQ * NQKV * 2;
  u16* Qb   = (u16*)(ws + off); off += (size_t)NH * TSEQ * HD * 2;
  u16* Kb   = (u16*)(ws + off); off += (size_t)NH * TSEQ * HD * 2;
  u16* Vb   = (u16*)(ws + off); off += (size_t)NH * TSEQ * HD * 2;
  u16* Ob   = (u16*)(ws + off); off += (size_t)TSEQ * DM * 2;
  float* sT = (float*)(ws + off); off += (size_t)TSEQ * 32 * 4;
  float* cT = (float*)(ws + off); off += (size_t)TSEQ * 32 * 4;

  // kv-split partials: g0 writes Ob directly; g1-3 alias qkvb (24MB, dead
  // after rope_reorg); stats alias wqb (2MB, dead after gemm1).
  u16*    Op123 = qkvb;
  float2* lmb   = (float2*)wqb;

  const int ncast = N4X + N4Q + N4P;
  cast3_kernel<<<(ncast + 255) / 256, 256, 0, stream>>>(x, xb, wqkv, wqb, wproj, wpb);
  rope_table<<<(TSEQ * 32) / 256, 256, 0, stream>>>(sT, cT);

  gemm_bt<1><<<dim3(NQKV / 128, TSEQ / 128), 256, 0, stream>>>(xb, wqb, qkvb, TSEQ, NQKV, DM);

  rope_reorg<<<(TSEQ * NH * 32) / 256, 256, 0, stream>>>(qkvb, sT, cT, Qb, Kb, Vb);

  fattn<<<NH * 64, 256, 0, stream>>>(Qb, Kb, Vb, Ob, Op123, lmb);

  merge_o<<<(TSEQ * DM / 8) / 256, 256, 0, stream>>>(Ob, Op123, lmb, Ob);

  gemm_bt<0><<<dim3(DM / 128, TSEQ / 128), 256, 0, stream>>>(Ob, wpb, out, TSEQ, DM, DM);
}